// Round 16
// baseline (109.487 us; speedup 1.0000x reference)
//
#include <hip/hip_runtime.h>

#define B_ 4
#define S_ 512
#define T_ 512
#define D_ 256
#define NSRC (B_ * S_)            // 2048 source rows
#define NROW 4096                 // src rows + tgt rows
#define K2F 2.8853900817779268f   // 2*log2(e): exp2(x*K2F) = e^(2x)

typedef __attribute__((ext_vector_type(8))) short short8;      // 8 bf16
typedef __attribute__((ext_vector_type(8))) _Float16 half8;    // 8 f16
typedef __attribute__((ext_vector_type(4))) float f32x4;
typedef __attribute__((ext_vector_type(2))) float f32x2;

__device__ __forceinline__ unsigned short f2bf(float f) {
    union { float f; unsigned u; } v; v.f = f;
    unsigned r = v.u + 0x7FFF + ((v.u >> 16) & 1);   // RNE
    return (unsigned short)(r >> 16);
}

// ---- packed f32 VOP3P helpers (hipcc scalarizes f32x2 arithmetic; these
// force v_pk_* at full rate). op_sel broadcasts kill all splat movs. ----
__device__ __forceinline__ f32x2 pkmul(f32x2 a, f32x2 b) {
    f32x2 d;
    asm("v_pk_mul_f32 %0, %1, %2" : "=v"(d) : "v"(a), "v"(b));
    return d;
}
__device__ __forceinline__ f32x2 pkfma(f32x2 a, f32x2 b, f32x2 c) {
    f32x2 d;
    asm("v_pk_fma_f32 %0, %1, %2, %3" : "=v"(d) : "v"(a), "v"(b), "v"(c));
    return d;
}
// res = a * broadcast(b.lo) (+ c)
__device__ __forceinline__ f32x2 pkmul_blo(f32x2 a, f32x2 b) {
    f32x2 d;
    asm("v_pk_mul_f32 %0, %1, %2 op_sel:[0,0] op_sel_hi:[1,0]"
        : "=v"(d) : "v"(a), "v"(b));
    return d;
}
__device__ __forceinline__ f32x2 pkfma_blo(f32x2 a, f32x2 b, f32x2 c) {
    f32x2 d;
    asm("v_pk_fma_f32 %0, %1, %2, %3 op_sel:[0,0,0] op_sel_hi:[1,0,1]"
        : "=v"(d) : "v"(a), "v"(b), "v"(c));
    return d;
}
// res = a * broadcast(b.hi) (+ c)
__device__ __forceinline__ f32x2 pkfma_bhi(f32x2 a, f32x2 b, f32x2 c) {
    f32x2 d;
    asm("v_pk_fma_f32 %0, %1, %2, %3 op_sel:[0,1,0] op_sel_hi:[1,1,1]"
        : "=v"(d) : "v"(a), "v"(b), "v"(c));
    return d;
}

// ---------------------------------------------------------------------------
// K1: ysyt+prob (VERBATIM R12-R15, proven). 768 blocks x 256 thr.
// ---------------------------------------------------------------------------
__global__ __launch_bounds__(256) void ysyt_kernel(
    const float* __restrict__ src, const float* __restrict__ tgt,
    const float* __restrict__ Wsrc, const float* __restrict__ Wtgt,
    const float* __restrict__ Wp,  const float* __restrict__ bp,
    const float* __restrict__ bsrc, const float* __restrict__ btgt,
    _Float16* __restrict__ ytr, float* __restrict__ out)
{
    __shared__ unsigned short lwt[16384];    // 32 KB
    __shared__ _Float16 ltb[64][72];         // 9.2 KB bounce tile
    const int bid = blockIdx.x, tid = threadIdx.x;
    const int lane = tid & 63, w = tid >> 6;

    if (bid < 256) {
        const int rowblk = bid >> 2, colq = bid & 3;
        const int R0 = rowblk * 64;
        const int n = lane & 15, quad = lane >> 4;
        const int mat = (R0 >= NSRC) ? 1 : 0;
        const float* bias = mat ? btgt : bsrc;
        const float* Wm = mat ? Wtgt : Wsrc;
        const float* xb = mat ? &tgt[(R0 - NSRC) * D_] : &src[R0 * D_];

        {   // W-slab transpose -> lwt
            const int r = tid;
            const int ksr = r >> 5, qr = (r >> 3) & 3, jr = r & 7;
            const int wbase = ksr * 512 + qr * 8 + jr;
            #pragma unroll 4
            for (int i = 0; i < 16; i++) {
                float4 v = *(const float4*)&Wm[r * D_ + colq * 64 + 4 * i];
                const int cc = 4 * i;
                lwt[((cc + 0) >> 4) * 4096 + ((cc + 0) & 15) * 32 + wbase] = f2bf(v.x);
                lwt[((cc + 1) >> 4) * 4096 + ((cc + 1) & 15) * 32 + wbase] = f2bf(v.y);
                lwt[((cc + 2) >> 4) * 4096 + ((cc + 2) & 15) * 32 + wbase] = f2bf(v.z);
                lwt[((cc + 3) >> 4) * 4096 + ((cc + 3) & 15) * 32 + wbase] = f2bf(v.w);
            }
        }

        short8 af[8];
        #pragma unroll
        for (int ks = 0; ks < 8; ks++) {
            const float* p = &xb[(w * 16 + n) * D_ + ks * 32 + quad * 8];
            float4 u0 = *(const float4*)p;
            float4 u1 = *(const float4*)(p + 4);
            short8 v;
            v[0] = (short)f2bf(u0.x); v[1] = (short)f2bf(u0.y);
            v[2] = (short)f2bf(u0.z); v[3] = (short)f2bf(u0.w);
            v[4] = (short)f2bf(u1.x); v[5] = (short)f2bf(u1.y);
            v[6] = (short)f2bf(u1.z); v[7] = (short)f2bf(u1.w);
            af[ks] = v;
        }
        __syncthreads();

        #pragma unroll
        for (int gc = 0; gc < 4; gc++) {
            const int gcol = colq * 4 + gc;
            const unsigned short* bp2 = &lwt[gc * 4096 + n * 32 + quad * 8];
            short8 bf[8];
            #pragma unroll
            for (int ks = 0; ks < 8; ks++) bf[ks] = *(const short8*)&bp2[ks * 512];
            f32x4 a4 = {0.f, 0.f, 0.f, 0.f};
            #pragma unroll
            for (int ks = 0; ks < 8; ks++)
                a4 = __builtin_amdgcn_mfma_f32_16x16x32_bf16(af[ks], bf[ks], a4, 0, 0, 0);
            const float bv = bias[gcol * 16 + n];
            const int rl = w * 16 + quad * 4;
            const int dl = gc * 16 + n;
            ltb[rl + 0][dl] = (_Float16)fminf(__builtin_amdgcn_exp2f((a4[0] + bv) * K2F), 60000.f);
            ltb[rl + 1][dl] = (_Float16)fminf(__builtin_amdgcn_exp2f((a4[1] + bv) * K2F), 60000.f);
            ltb[rl + 2][dl] = (_Float16)fminf(__builtin_amdgcn_exp2f((a4[2] + bv) * K2F), 60000.f);
            ltb[rl + 3][dl] = (_Float16)fminf(__builtin_amdgcn_exp2f((a4[3] + bv) * K2F), 60000.f);
        }
        __syncthreads();
        {
            const int row = tid >> 2, seg = tid & 3;
            half8 v0 = *(const half8*)&ltb[row][seg * 16];
            half8 v1 = *(const half8*)&ltb[row][seg * 16 + 8];
            _Float16* dst = &ytr[(size_t)(R0 + row) * D_ + colq * 64 + seg * 16];
            *(half8*)&dst[0] = v0;
            *(half8*)&dst[8] = v1;
        }
    } else {
        int row  = (bid - 256) * 4 + w;
        float p0 = 0.f, p1 = 0.f;
        #pragma unroll
        for (int i = 0; i < 4; i++) {
            int d = lane + i * 64;
            float v = tgt[row * D_ + d];
            float2 wv = *(const float2*)&Wp[d * 2];
            p0 = fmaf(v, wv.x, p0);
            p1 = fmaf(v, wv.y, p1);
        }
        #pragma unroll
        for (int off = 32; off > 0; off >>= 1) {
            p0 += __shfl_down(p0, off, 64);
            p1 += __shfl_down(p1, off, 64);
        }
        if (lane == 0) {
            const float L2E = 1.4426950408889634f;
            float l0 = p0 + bp[0], l1 = p1 + bp[1];
            float e10 = __builtin_amdgcn_exp2f((l1 - l0) * L2E);
            float e01 = __builtin_amdgcn_exp2f((l0 - l1) * L2E);
            out[B_ * T_ * S_ + row * 2 + 0] = __builtin_amdgcn_rcpf(1.f + e10);
            out[B_ * T_ * S_ + row * 2 + 1] = __builtin_amdgcn_rcpf(1.f + e01);
        }
    }
}

// ---------------------------------------------------------------------------
// K2: genp v12 — R13/R14 proven skeleton + PACKED-F32 fold (inline asm).
// R14 counters: VALU-bound, ~203 inst/kq = fold scalarized by hipcc.
// v12: fold in v_pk_fma_f32/v_pk_mul_f32 with op_sel broadcasts (t lo/hi
// per t-row; w-pair lo/hi per term) -> ~115 inst/kq, inst/term 6.3 -> 3.5.
// Operation order IDENTICAL to the passing scalar fold -> same numerics.
// 32s x 32t, f16 full-D single-barrier tile, 4 blk/CU, Wres in LDS,
// plain stores. genP = C0 - 2 * sum_d w_d / (1 + ys*yt).
// ---------------------------------------------------------------------------
__global__ __launch_bounds__(256) void genp_kernel(
    const _Float16* __restrict__ ytr,   // [4096][256]
    const float* __restrict__ Wres, const float* __restrict__ bres,
    float* __restrict__ out)
{
    __shared__ _Float16 lys[32][264];   // 16.9 KB
    __shared__ _Float16 lyt[32][264];   // 16.9 KB
    __shared__ float lw[256];           // 1 KB

    const int tid = threadIdx.x;
    const int lane = tid & 63;
    const int s0 = blockIdx.x * 32;
    const int t0 = blockIdx.y * 32;
    const int b  = blockIdx.z;
    const int m  = tid & 15;             // s rows m, m+16
    const int g  = tid >> 4;             // t rows g, g+16  (0..15)

    // ---- stage ALL 256 d + Wres in one burst, one barrier ----
    {
        const int srow = tid >> 3;       // 0..31
        const int seg  = tid & 7;        // 0..7, 32 halves each
        const size_t gs = (size_t)(b * S_ + s0 + srow) * D_ + seg * 32;
        const size_t gt = (size_t)(NSRC + b * T_ + t0 + srow) * D_ + seg * 32;
        #pragma unroll
        for (int j = 0; j < 4; j++) {
            *(half8*)&lys[srow][seg * 32 + 8 * j] = *(const half8*)&ytr[gs + 8 * j];
            *(half8*)&lyt[srow][seg * 32 + 8 * j] = *(const half8*)&ytr[gt + 8 * j];
        }
        if (tid < 64) *(float4*)&lw[4 * tid] = *(const float4*)&Wres[4 * tid];
    }
    __syncthreads();                     // the ONLY barrier

    float a0x = 0.f, a0y = 0.f, a1x = 0.f, a1y = 0.f;
    const f32x2 one2 = {1.f, 1.f};

    #pragma unroll 2
    for (int kq = 0; kq < 32; kq++) {
        half8 sL = *(const half8*)&lys[m][8 * kq];
        half8 sH = *(const half8*)&lys[m + 16][8 * kq];
        half8 tL = *(const half8*)&lyt[g][8 * kq];
        half8 tH = *(const half8*)&lyt[g + 16][8 * kq];
        f32x2 sp[8], tp[8], wp[4];
        #pragma unroll
        for (int k = 0; k < 8; k++) {
            sp[k] = (f32x2){(float)sL[k], (float)sH[k]};   // lo=s(m), hi=s(m+16)
            tp[k] = (f32x2){(float)tL[k], (float)tH[k]};   // lo=t(g), hi=t(g+16)
        }
        #pragma unroll
        for (int j = 0; j < 4; j++)
            wp[j] = *(const f32x2*)&lw[8 * kq + 2 * j];    // (w2j, w2j+1)

        // 8-term rcp fold, packed; DDFN selects t lo (row g) / hi (row g+16)
        #define PFOLD(ACCX, ACCY, DDFN) {                                     \
            f32x2 dd0 = DDFN(sp[0], tp[0], one2);                             \
            f32x2 dd1 = DDFN(sp[1], tp[1], one2);                             \
            f32x2 dd2 = DDFN(sp[2], tp[2], one2);                             \
            f32x2 dd3 = DDFN(sp[3], tp[3], one2);                             \
            f32x2 dd4 = DDFN(sp[4], tp[4], one2);                             \
            f32x2 dd5 = DDFN(sp[5], tp[5], one2);                             \
            f32x2 dd6 = DDFN(sp[6], tp[6], one2);                             \
            f32x2 dd7 = DDFN(sp[7], tp[7], one2);                             \
            f32x2 p01 = pkmul(dd0, dd1);                                      \
            f32x2 p23 = pkmul(dd2, dd3);                                      \
            f32x2 p45 = pkmul(dd4, dd5);                                      \
            f32x2 p67 = pkmul(dd6, dd7);                                      \
            f32x2 q03 = pkmul(p01, p23);                                      \
            f32x2 q47 = pkmul(p45, p67);                                      \
            f32x2 den = pkmul(q03, q47);                                      \
            f32x2 u01 = pkmul_blo(dd1, wp[0]);                                \
            u01 = pkfma_bhi(dd0, wp[0], u01);                                 \
            f32x2 u23 = pkmul_blo(dd3, wp[1]);                                \
            u23 = pkfma_bhi(dd2, wp[1], u23);                                 \
            f32x2 u45 = pkmul_blo(dd5, wp[2]);                                \
            u45 = pkfma_bhi(dd4, wp[2], u45);                                 \
            f32x2 u67 = pkmul_blo(dd7, wp[3]);                                \
            u67 = pkfma_bhi(dd6, wp[3], u67);                                 \
            f32x2 n03 = pkmul(u01, p23);                                      \
            n03 = pkfma(u23, p01, n03);                                       \
            f32x2 n47 = pkmul(u45, p67);                                      \
            n47 = pkfma(u67, p45, n47);                                       \
            f32x2 num = pkmul(n03, q47);                                      \
            num = pkfma(n47, q03, num);                                       \
            float rx = __builtin_amdgcn_rcpf(den.x);                          \
            float ry = __builtin_amdgcn_rcpf(den.y);                          \
            ACCX = fmaf(num.x, rx, ACCX);                                     \
            ACCY = fmaf(num.y, ry, ACCY);                                     \
        }
        PFOLD(a0x, a0y, pkfma_blo)   // t row g
        PFOLD(a1x, a1y, pkfma_bhi)   // t row g+16
        #undef PFOLD
    }

    // C0 per-wave butterfly; plain stores
    float cw = Wres[lane] + Wres[lane + 64] + Wres[lane + 128] + Wres[lane + 192];
    #pragma unroll
    for (int off = 32; off > 0; off >>= 1) cw += __shfl_xor(cw, off, 64);
    const float C0 = cw + bres[0];

    out[(size_t)(b * T_ + t0 + g     ) * S_ + s0 + m     ] = C0 - 2.f * a0x;
    out[(size_t)(b * T_ + t0 + g     ) * S_ + s0 + m + 16] = C0 - 2.f * a0y;
    out[(size_t)(b * T_ + t0 + g + 16) * S_ + s0 + m     ] = C0 - 2.f * a1x;
    out[(size_t)(b * T_ + t0 + g + 16) * S_ + s0 + m + 16] = C0 - 2.f * a1y;
}

extern "C" void kernel_launch(void* const* d_in, const int* in_sizes, int n_in,
                              void* d_out, int out_size, void* d_ws, size_t ws_size,
                              hipStream_t stream) {
    const float* source = (const float*)d_in[0];
    const float* target = (const float*)d_in[1];
    const float* W_src  = (const float*)d_in[2];
    const float* b_src  = (const float*)d_in[3];
    const float* W_tgt  = (const float*)d_in[4];
    const float* b_tgt  = (const float*)d_in[5];
    const float* W_res  = (const float*)d_in[6];
    const float* b_res  = (const float*)d_in[7];
    const float* W_prob = (const float*)d_in[8];
    const float* b_prob = (const float*)d_in[9];
    float* out = (float*)d_out;

    _Float16* ytr = (_Float16*)d_ws;           // [4096][256] f16 = 2 MB

    ysyt_kernel<<<768, 256, 0, stream>>>(source, target, W_src, W_tgt,
                                         W_prob, b_prob, b_src, b_tgt,
                                         ytr, out);
    genp_kernel<<<dim3(16, 16, 4), 256, 0, stream>>>(ytr, W_res, b_res, out);
}

// Round 17
// 105.377 us; speedup vs baseline: 1.0390x; 1.0390x over previous
//
#include <hip/hip_runtime.h>

#define B_ 4
#define S_ 512
#define T_ 512
#define D_ 256
#define NSRC (B_ * S_)            // 2048 source rows
#define NROW 4096                 // src rows + tgt rows
#define K2F 2.8853900817779268f   // 2*log2(e): exp2(x*K2F) = e^(2x)

typedef __attribute__((ext_vector_type(8))) short short8;   // 8 bf16
typedef __attribute__((ext_vector_type(4))) float f32x4;
typedef __attribute__((ext_vector_type(2))) float f32x2;

__device__ __forceinline__ unsigned short f2bf(float f) {
    union { float f; unsigned u; } v; v.f = f;
    unsigned r = v.u + 0x7FFF + ((v.u >> 16) & 1);   // RNE
    return (unsigned short)(r >> 16);
}

// ---------------------------------------------------------------------------
// K1: ysyt+prob (R9 best-measured configuration). 768 blocks x 256 thr.
//  blocks 0..255:  ysyt with PER-BLOCK W-slab LDS transpose; writes
//                  yst[d][global_row] f32 (transposed via MFMA D-layout).
//  blocks 256..767: prob softmax, 4 rows each.
// ---------------------------------------------------------------------------
__global__ __launch_bounds__(256) void ysyt_kernel(
    const float* __restrict__ src, const float* __restrict__ tgt,
    const float* __restrict__ Wsrc, const float* __restrict__ Wtgt,
    const float* __restrict__ Wp,  const float* __restrict__ bp,
    const float* __restrict__ bsrc, const float* __restrict__ btgt,
    float* __restrict__ yst, float* __restrict__ out)
{
    __shared__ unsigned short lwt[16384];    // 32 KB
    const int bid = blockIdx.x, tid = threadIdx.x;
    const int lane = tid & 63, w = tid >> 6;

    if (bid < 256) {
        const int rowblk = bid >> 2, colq = bid & 3;
        const int R0 = rowblk * 64;
        const int n = lane & 15, quad = lane >> 4;
        const int mat = (R0 >= NSRC) ? 1 : 0;
        const float* bias = mat ? btgt : bsrc;
        const float* Wm = mat ? Wtgt : Wsrc;
        const float* xb = mat ? &tgt[(R0 - NSRC) * D_] : &src[R0 * D_];

        // ---- build W-slab transpose in LDS ----
        {
            const int r = tid;
            const int ksr = r >> 5, qr = (r >> 3) & 3, jr = r & 7;
            const int wbase = ksr * 512 + qr * 8 + jr;
            #pragma unroll 4
            for (int i = 0; i < 16; i++) {
                float4 v = *(const float4*)&Wm[r * D_ + colq * 64 + 4 * i];
                const int cc = 4 * i;
                lwt[((cc + 0) >> 4) * 4096 + ((cc + 0) & 15) * 32 + wbase] = f2bf(v.x);
                lwt[((cc + 1) >> 4) * 4096 + ((cc + 1) & 15) * 32 + wbase] = f2bf(v.y);
                lwt[((cc + 2) >> 4) * 4096 + ((cc + 2) & 15) * 32 + wbase] = f2bf(v.z);
                lwt[((cc + 3) >> 4) * 4096 + ((cc + 3) & 15) * 32 + wbase] = f2bf(v.w);
            }
        }

        // ---- A fragments ----
        short8 af[8];
        #pragma unroll
        for (int ks = 0; ks < 8; ks++) {
            const float* p = &xb[(w * 16 + n) * D_ + ks * 32 + quad * 8];
            float4 u0 = *(const float4*)p;
            float4 u1 = *(const float4*)(p + 4);
            short8 v;
            v[0] = (short)f2bf(u0.x); v[1] = (short)f2bf(u0.y);
            v[2] = (short)f2bf(u0.z); v[3] = (short)f2bf(u0.w);
            v[4] = (short)f2bf(u1.x); v[5] = (short)f2bf(u1.y);
            v[6] = (short)f2bf(u1.z); v[7] = (short)f2bf(u1.w);
            af[ks] = v;
        }
        __syncthreads();

        // ---- MFMA + exp2 + transposed store ----
        #pragma unroll
        for (int gc = 0; gc < 4; gc++) {
            const int gcol = colq * 4 + gc;
            const unsigned short* bp2 = &lwt[gc * 4096 + n * 32 + quad * 8];
            short8 bf[8];
            #pragma unroll
            for (int ks = 0; ks < 8; ks++) bf[ks] = *(const short8*)&bp2[ks * 512];
            f32x4 a4 = {0.f, 0.f, 0.f, 0.f};
            #pragma unroll
            for (int ks = 0; ks < 8; ks++)
                a4 = __builtin_amdgcn_mfma_f32_16x16x32_bf16(af[ks], bf[ks], a4, 0, 0, 0);
            const float bv = bias[gcol * 16 + n];
            float4 o;
            o.x = __builtin_amdgcn_exp2f((a4[0] + bv) * K2F);
            o.y = __builtin_amdgcn_exp2f((a4[1] + bv) * K2F);
            o.z = __builtin_amdgcn_exp2f((a4[2] + bv) * K2F);
            o.w = __builtin_amdgcn_exp2f((a4[3] + bv) * K2F);
            *(float4*)&yst[(gcol * 16 + n) * NROW + R0 + w * 16 + quad * 4] = o;
        }
    } else {
        // ---- prob softmax ----
        int row  = (bid - 256) * 4 + w;
        float p0 = 0.f, p1 = 0.f;
        #pragma unroll
        for (int i = 0; i < 4; i++) {
            int d = lane + i * 64;
            float v = tgt[row * D_ + d];
            float2 wv = *(const float2*)&Wp[d * 2];
            p0 = fmaf(v, wv.x, p0);
            p1 = fmaf(v, wv.y, p1);
        }
        #pragma unroll
        for (int off = 32; off > 0; off >>= 1) {
            p0 += __shfl_down(p0, off, 64);
            p1 += __shfl_down(p1, off, 64);
        }
        if (lane == 0) {
            const float L2E = 1.4426950408889634f;
            float l0 = p0 + bp[0], l1 = p1 + bp[1];
            float e10 = __builtin_amdgcn_exp2f((l1 - l0) * L2E);
            float e01 = __builtin_amdgcn_exp2f((l0 - l1) * L2E);
            out[B_ * T_ * S_ + row * 2 + 0] = __builtin_amdgcn_rcpf(1.f + e10);
            out[B_ * T_ * S_ + row * 2 + 1] = __builtin_amdgcn_rcpf(1.f + e01);
        }
    }
}

// ---------------------------------------------------------------------------
// K2: genp v1 (best measured). Tile 32s x 32t, grid (16,16,4) = 1024 blocks,
// 256 thr, 4 blocks/CU (LDS 37KB). d-chunks of 64, double-buffered;
// 2s x 2t per thread, 8-term rcp folding.
// genP = C0 - 2 * sum_d w_d / (1 + ys*yt),  C0 = sum w + b_res.
// ---------------------------------------------------------------------------
#define CLS 36
__global__ __launch_bounds__(256) void genp_kernel(
    const float* __restrict__ yst,
    const float* __restrict__ Wres, const float* __restrict__ bres,
    float* __restrict__ out)
{
    __shared__ float lys[2][64][CLS];
    __shared__ float lyt[2][64][CLS];
    __shared__ float c0s;

    const int tid = threadIdx.x;
    const int lane = tid & 63, w = tid >> 6;
    const int s0 = blockIdx.x * 32;
    const int t0 = blockIdx.y * 32;
    const int b  = blockIdx.z;
    const int m = tid & 15;            // s-pair: s0 + 2m, 2m+1
    const int g = tid >> 4;            // t-pair: t0 + 2g, 2g+1
    const int r = tid >> 3;            // staging row 0..31
    const int q = tid & 7;             // staging quad 0..7

    if (w == 0) {
        float s = Wres[lane] + Wres[lane + 64] + Wres[lane + 128] + Wres[lane + 192];
        #pragma unroll
        for (int off = 32; off > 0; off >>= 1) s += __shfl_xor(s, off, 64);
        if (lane == 0) c0s = s + bres[0];
    }

    const int ysbase = b * S_ + s0;
    const int ytbase = NSRC + b * T_ + t0;

    {
        float4 a0 = *(const float4*)&yst[(r)      * NROW + ysbase + 4 * q];
        float4 a1 = *(const float4*)&yst[(r + 32) * NROW + ysbase + 4 * q];
        float4 b0 = *(const float4*)&yst[(r)      * NROW + ytbase + 4 * q];
        float4 b1 = *(const float4*)&yst[(r + 32) * NROW + ytbase + 4 * q];
        *(float4*)&lys[0][r][4 * q]      = a0;
        *(float4*)&lys[0][r + 32][4 * q] = a1;
        *(float4*)&lyt[0][r][4 * q]      = b0;
        *(float4*)&lyt[0][r + 32][4 * q] = b1;
    }
    __syncthreads();

    f32x2 acc[2];
    acc[0] = (f32x2){0.f, 0.f};
    acc[1] = (f32x2){0.f, 0.f};
    const f32x2 one2 = {1.f, 1.f};

    for (int c = 0; c < 4; c++) {
        const int bi = c & 1;
        float4 pa0, pa1, pb0, pb1;
        if (c < 3) {
            const int dn = (c + 1) * 64;
            pa0 = *(const float4*)&yst[(dn + r)      * NROW + ysbase + 4 * q];
            pa1 = *(const float4*)&yst[(dn + r + 32) * NROW + ysbase + 4 * q];
            pb0 = *(const float4*)&yst[(dn + r)      * NROW + ytbase + 4 * q];
            pb1 = *(const float4*)&yst[(dn + r + 32) * NROW + ytbase + 4 * q];
        }

        const float* wp = &Wres[c * 64];
        #pragma unroll 2
        for (int kq = 0; kq < 8; kq++) {
            const int d0 = 8 * kq;
            f32x2 ap[8];
            float2 ct[8];
            f32x2 wv[8];
            #pragma unroll
            for (int k = 0; k < 8; k++) {
                float2 a2 = *(const float2*)&lys[bi][d0 + k][2 * m];
                ct[k] = *(const float2*)&lyt[bi][d0 + k][2 * g];
                ap[k] = (f32x2){a2.x, a2.y};
                const float wk = wp[d0 + k];     // uniform s_load
                wv[k] = (f32x2){wk, wk};
            }
            #pragma unroll
            for (int i = 0; i < 2; i++) {
                const float c0 = i ? ct[0].y : ct[0].x;
                f32x2 dd[8];
                #pragma unroll
                for (int k = 0; k < 8; k++) {
                    const float cv = i ? ct[k].y : ct[k].x;
                    const f32x2 cs = {cv, cv};
                    dd[k] = ap[k] * cs + one2;   // 1 + ys*yt
                }
                f32x2 p01 = dd[0] * dd[1];
                f32x2 p23 = dd[2] * dd[3];
                f32x2 p45 = dd[4] * dd[5];
                f32x2 p67 = dd[6] * dd[7];
                f32x2 q03 = p01 * p23;
                f32x2 q47 = p45 * p67;
                f32x2 den = q03 * q47;
                f32x2 u01 = dd[1] * wv[0]; u01 = dd[0] * wv[1] + u01;
                f32x2 u23 = dd[3] * wv[2]; u23 = dd[2] * wv[3] + u23;
                f32x2 u45 = dd[5] * wv[4]; u45 = dd[4] * wv[5] + u45;
                f32x2 u67 = dd[7] * wv[6]; u67 = dd[6] * wv[7] + u67;
                f32x2 n03 = u01 * p23; n03 = u23 * p01 + n03;
                f32x2 n47 = u45 * p67; n47 = u67 * p45 + n47;
                f32x2 num = n03 * q47; num = n47 * q03 + num;
                f32x2 rr;
                rr.x = __builtin_amdgcn_rcpf(den.x);
                rr.y = __builtin_amdgcn_rcpf(den.y);
                acc[i] = num * rr + acc[i];
                (void)c0;
            }
        }

        if (c < 3) {
            *(float4*)&lys[bi ^ 1][r][4 * q]      = pa0;
            *(float4*)&lys[bi ^ 1][r + 32][4 * q] = pa1;
            *(float4*)&lyt[bi ^ 1][r][4 * q]      = pb0;
            *(float4*)&lyt[bi ^ 1][r + 32][4 * q] = pb1;
        }
        __syncthreads();
    }

    const float C0 = c0s;
    #pragma unroll
    for (int i = 0; i < 2; i++) {
        float2 o;
        o.x = C0 - 2.f * acc[i].x;
        o.y = C0 - 2.f * acc[i].y;
        *(float2*)&out[(b * T_ + t0 + 2 * g + i) * S_ + s0 + 2 * m] = o;
    }
}

extern "C" void kernel_launch(void* const* d_in, const int* in_sizes, int n_in,
                              void* d_out, int out_size, void* d_ws, size_t ws_size,
                              hipStream_t stream) {
    const float* source = (const float*)d_in[0];
    const float* target = (const float*)d_in[1];
    const float* W_src  = (const float*)d_in[2];
    const float* b_src  = (const float*)d_in[3];
    const float* W_tgt  = (const float*)d_in[4];
    const float* b_tgt  = (const float*)d_in[5];
    const float* W_res  = (const float*)d_in[6];
    const float* b_res  = (const float*)d_in[7];
    const float* W_prob = (const float*)d_in[8];
    const float* b_prob = (const float*)d_in[9];
    float* out = (float*)d_out;

    float* yst = (float*)d_ws;                 // [256][4096] f32 = 4 MB

    ysyt_kernel<<<768, 256, 0, stream>>>(source, target, W_src, W_tgt,
                                         W_prob, b_prob, b_src, b_tgt,
                                         yst, out);
    genp_kernel<<<dim3(16, 16, 4), 256, 0, stream>>>(yst, W_res, b_res, out);
}